// Round 2
// baseline (285.311 us; speedup 1.0000x reference)
//
#include <hip/hip_runtime.h>
#include <math.h>

// -------- physical constants (from reference) --------
#define C_ELE   332.0637f
#define C_EWF   1.12837917f
#define C_EWP   0.3275911f
#define C_A0    0.254829592f
#define C_A1   -0.284496736f
#define C_A2    1.421413741f
#define C_A3   -1.453152027f
#define C_A4    1.061405429f
#define C_BETA  18.7f
#define C_R0    2.2f
#define C_GEW   0.3f
#define C_45P6  8303.765625f   // 4.5^6
#define C_DC6I  1e-6f          // 1 / DISP_CUTOFF^6

// native clang vector types (required by __builtin_nontemporal_*)
typedef float vf4 __attribute__((ext_vector_type(4)));
typedef int   vi4 __attribute__((ext_vector_type(4)));

__device__ __forceinline__ float frcp(float x) { return __builtin_amdgcn_rcpf(x); }

struct EdgeOut { float ec, fx, fy, fz, ed, gx, gy, gz; };

__device__ __forceinline__ EdgeOut edge_compute(
    int r, int c, float dx, float dy, float dz,
    const float* __restrict__ charge, const float* __restrict__ c6a,
    const float* __restrict__ r0a)
{
    float r2   = dx * dx + dy * dy + dz * dz;
    float rij  = sqrtf(r2);
    float rinv = frcp(rij);

    // ---- Coulomb ----
    float pref = C_ELE * charge[r] * charge[c] * rinv;
    float x    = (C_BETA / C_R0) * (rij - C_R0);
    float ax   = fabsf(x);
    float ex   = __expf(-ax);                 // exp(-|x|), safe for |x| up to ~66
    float den  = frcp(1.0f + ex);
    float damp = (x >= 0.0f) ? den : ex * den;          // sigmoid(x), stable
    float sp   = (fmaxf(x, 0.0f) + __logf(1.0f + ex)) * (1.0f / C_BETA); // softplus(x)/beta
    float s    = rij * (1.0f / C_R0) * frcp(1.0f + sp);

    float grij  = C_GEW * rij;
    float expm2 = __expf(-grij * grij);
    float t     = frcp(1.0f + C_EWP * grij);
    float erfc  = t * (C_A0 + t * (C_A1 + t * (C_A2 + t * (C_A3 + t * C_A4)))) * expm2;

    EdgeOut o;
    o.ec = pref * (s + erfc - 1.0f);
    float fcl = pref * (damp * s * s + erfc + C_EWF * grij * expm2 - 1.0f);
    float fsc = fcl * frcp(r2);
    o.fx = dx * fsc; o.fy = dy * fsc; o.fz = dz * fsc;

    // ---- Dispersion (D3-CSO) ----
    float c6ij  = sqrtf(c6a[r] * c6a[c]);
    float r0ij  = 0.5f * (r0a[r] + r0a[c]);
    float r6    = r2 * r2 * r2 + C_45P6;
    float r6i   = frcp(r6);
    float e     = __expf(rij - 2.5f * r0ij);  // exponent in [-9, 5]
    float onep  = frcp(1.0f + e);
    float cso   = 0.85f + 0.82f * onep;
    o.ed = -c6ij * r6i * cso + c6ij * C_DC6I;
    float r5  = r2 * r2 * rij;
    float fd  = -6.0f * c6ij * r5 * r6i * r6i * cso - c6ij * r6i * (0.82f * e * onep * onep);
    float gsc = fd * rinv;
    o.gx = dx * gsc; o.gy = dy * gsc; o.gz = dz * gsc;
    return o;
}

// 4 edges per thread: all streamed traffic is 16 B/lane vectorized.
__global__ __launch_bounds__(256) void bamboo_vec4(
    const int* __restrict__ row, const int* __restrict__ col,
    const float* __restrict__ dij,
    const float* __restrict__ charge, const float* __restrict__ c6a,
    const float* __restrict__ r0a,
    float* __restrict__ out, int E)
{
    int g    = blockIdx.x * blockDim.x + threadIdx.x;
    int base = g * 4;
    if (base >= E) return;

    float* __restrict__ ec_o = out;
    float* __restrict__ cf_o = out + (size_t)E;
    float* __restrict__ ed_o = out + (size_t)4 * E;
    float* __restrict__ df_o = out + (size_t)5 * E;

    if (base + 4 <= E) {
        vi4 rr = __builtin_nontemporal_load((const vi4*)(row + base));
        vi4 cc = __builtin_nontemporal_load((const vi4*)(col + base));
        const float* dp = dij + (size_t)base * 3;
        vf4 d0 = __builtin_nontemporal_load((const vf4*)(dp + 0));
        vf4 d1 = __builtin_nontemporal_load((const vf4*)(dp + 4));
        vf4 d2 = __builtin_nontemporal_load((const vf4*)(dp + 8));

        EdgeOut o0 = edge_compute(rr.x, cc.x, d0.x, d0.y, d0.z, charge, c6a, r0a);
        EdgeOut o1 = edge_compute(rr.y, cc.y, d0.w, d1.x, d1.y, charge, c6a, r0a);
        EdgeOut o2 = edge_compute(rr.z, cc.z, d1.z, d1.w, d2.x, charge, c6a, r0a);
        EdgeOut o3 = edge_compute(rr.w, cc.w, d2.y, d2.z, d2.w, charge, c6a, r0a);

        vf4 ec4 = { o0.ec, o1.ec, o2.ec, o3.ec };
        vf4 ed4 = { o0.ed, o1.ed, o2.ed, o3.ed };
        __builtin_nontemporal_store(ec4, (vf4*)(ec_o + base));
        __builtin_nontemporal_store(ed4, (vf4*)(ed_o + base));

        vf4 f0 = { o0.fx, o0.fy, o0.fz, o1.fx };
        vf4 f1 = { o1.fy, o1.fz, o2.fx, o2.fy };
        vf4 f2 = { o2.fz, o3.fx, o3.fy, o3.fz };
        float* cfp = cf_o + (size_t)base * 3;
        __builtin_nontemporal_store(f0, (vf4*)(cfp + 0));
        __builtin_nontemporal_store(f1, (vf4*)(cfp + 4));
        __builtin_nontemporal_store(f2, (vf4*)(cfp + 8));

        vf4 g0 = { o0.gx, o0.gy, o0.gz, o1.gx };
        vf4 g1 = { o1.gy, o1.gz, o2.gx, o2.gy };
        vf4 g2 = { o2.gz, o3.gx, o3.gy, o3.gz };
        float* dfp = df_o + (size_t)base * 3;
        __builtin_nontemporal_store(g0, (vf4*)(dfp + 0));
        __builtin_nontemporal_store(g1, (vf4*)(dfp + 4));
        __builtin_nontemporal_store(g2, (vf4*)(dfp + 8));
    } else {
        for (int j = base; j < E; ++j) {
            EdgeOut o = edge_compute(row[j], col[j],
                                     dij[3 * (size_t)j], dij[3 * (size_t)j + 1], dij[3 * (size_t)j + 2],
                                     charge, c6a, r0a);
            ec_o[j] = o.ec; ed_o[j] = o.ed;
            cf_o[3 * (size_t)j] = o.fx; cf_o[3 * (size_t)j + 1] = o.fy; cf_o[3 * (size_t)j + 2] = o.fz;
            df_o[3 * (size_t)j] = o.gx; df_o[3 * (size_t)j + 1] = o.gy; df_o[3 * (size_t)j + 2] = o.gz;
        }
    }
}

// Fallback if E % 4 != 0 (vector-write alignment of out+E/out+5E needs E%4==0).
__global__ __launch_bounds__(256) void bamboo_scalar(
    const int* __restrict__ row, const int* __restrict__ col,
    const float* __restrict__ dij,
    const float* __restrict__ charge, const float* __restrict__ c6a,
    const float* __restrict__ r0a,
    float* __restrict__ out, int E)
{
    int j = blockIdx.x * blockDim.x + threadIdx.x;
    if (j >= E) return;
    float* ec_o = out;
    float* cf_o = out + (size_t)E;
    float* ed_o = out + (size_t)4 * E;
    float* df_o = out + (size_t)5 * E;
    EdgeOut o = edge_compute(row[j], col[j],
                             dij[3 * (size_t)j], dij[3 * (size_t)j + 1], dij[3 * (size_t)j + 2],
                             charge, c6a, r0a);
    ec_o[j] = o.ec; ed_o[j] = o.ed;
    cf_o[3 * (size_t)j] = o.fx; cf_o[3 * (size_t)j + 1] = o.fy; cf_o[3 * (size_t)j + 2] = o.fz;
    df_o[3 * (size_t)j] = o.gx; df_o[3 * (size_t)j + 1] = o.gy; df_o[3 * (size_t)j + 2] = o.gz;
}

extern "C" void kernel_launch(void* const* d_in, const int* in_sizes, int n_in,
                              void* d_out, int out_size, void* d_ws, size_t ws_size,
                              hipStream_t stream) {
    const int*   row    = (const int*)d_in[0];
    const int*   col    = (const int*)d_in[1];
    const float* dij    = (const float*)d_in[2];
    const float* charge = (const float*)d_in[3];
    const float* c6a    = (const float*)d_in[4];
    const float* r0a    = (const float*)d_in[5];
    float* out = (float*)d_out;
    int E = in_sizes[0];

    if ((E & 3) == 0) {
        int groups = E / 4;
        int blocks = (groups + 255) / 256;
        bamboo_vec4<<<blocks, 256, 0, stream>>>(row, col, dij, charge, c6a, r0a, out, E);
    } else {
        int blocks = (E + 255) / 256;
        bamboo_scalar<<<blocks, 256, 0, stream>>>(row, col, dij, charge, c6a, r0a, out, E);
    }
}

// Round 3
// 240.721 us; speedup vs baseline: 1.1852x; 1.1852x over previous
//
#include <hip/hip_runtime.h>
#include <math.h>

// -------- physical constants (from reference) --------
#define C_ELE   332.0637f
#define C_EWF   1.12837917f
#define C_EWP   0.3275911f
#define C_A0    0.254829592f
#define C_A1   -0.284496736f
#define C_A2    1.421413741f
#define C_A3   -1.453152027f
#define C_A4    1.061405429f
#define C_BETA  18.7f
#define C_R0    2.2f
#define C_GEW   0.3f
#define C_45P6  8303.765625f   // 4.5^6
#define C_DC6I  1e-6f          // 1 / DISP_CUTOFF^6

typedef float vf4 __attribute__((ext_vector_type(4)));
typedef int   vi4 __attribute__((ext_vector_type(4)));

__device__ __forceinline__ float frcp(float x) { return __builtin_amdgcn_rcpf(x); }

struct EdgeOut { float ec, fx, fy, fz, ed, gx, gy, gz; };

// ar/ac = packed atom records: {charge, c6, r0, pad}
__device__ __forceinline__ EdgeOut edge_compute(
    vf4 ar, vf4 ac, float dx, float dy, float dz)
{
    float r2   = dx * dx + dy * dy + dz * dz;
    float rij  = sqrtf(r2);
    float rinv = frcp(rij);

    // ---- Coulomb ----
    float pref = C_ELE * ar.x * ac.x * rinv;
    float x    = (C_BETA / C_R0) * (rij - C_R0);
    float ax   = fabsf(x);
    float ex   = __expf(-ax);                 // exp(-|x|), stable
    float den  = frcp(1.0f + ex);
    float damp = (x >= 0.0f) ? den : ex * den;          // sigmoid(x)
    float sp   = (fmaxf(x, 0.0f) + __logf(1.0f + ex)) * (1.0f / C_BETA); // softplus(x)/beta
    float s    = rij * (1.0f / C_R0) * frcp(1.0f + sp);

    float grij  = C_GEW * rij;
    float expm2 = __expf(-grij * grij);
    float t     = frcp(1.0f + C_EWP * grij);
    float erfc  = t * (C_A0 + t * (C_A1 + t * (C_A2 + t * (C_A3 + t * C_A4)))) * expm2;

    EdgeOut o;
    o.ec = pref * (s + erfc - 1.0f);
    float fcl = pref * (damp * s * s + erfc + C_EWF * grij * expm2 - 1.0f);
    float fsc = fcl * frcp(r2);
    o.fx = dx * fsc; o.fy = dy * fsc; o.fz = dz * fsc;

    // ---- Dispersion (D3-CSO) ----
    float c6ij  = sqrtf(ar.y * ac.y);
    float r0ij  = 0.5f * (ar.z + ac.z);
    float r6    = r2 * r2 * r2 + C_45P6;
    float r6i   = frcp(r6);
    float e     = __expf(rij - 2.5f * r0ij);
    float onep  = frcp(1.0f + e);
    float cso   = 0.85f + 0.82f * onep;
    o.ed = -c6ij * r6i * cso + c6ij * C_DC6I;
    float r5  = r2 * r2 * rij;
    float fd  = -6.0f * c6ij * r5 * r6i * r6i * cso - c6ij * r6i * (0.82f * e * onep * onep);
    float gsc = fd * rinv;
    o.gx = dx * gsc; o.gy = dy * gsc; o.gz = dz * gsc;
    return o;
}

// Prologue: pack (charge, c6, r0) into one 16B record per atom in d_ws.
__global__ __launch_bounds__(256) void pack_atoms(
    const float* __restrict__ charge, const float* __restrict__ c6a,
    const float* __restrict__ r0a, vf4* __restrict__ tbl, int N)
{
    int i = blockIdx.x * blockDim.x + threadIdx.x;
    if (i < N) {
        vf4 v = { charge[i], c6a[i], r0a[i], 0.0f };
        tbl[i] = v;
    }
}

// 4 edges per thread: streamed traffic 16B/lane; 8 clustered 16B gathers.
__global__ __launch_bounds__(256) void bamboo_vec4(
    const int* __restrict__ row, const int* __restrict__ col,
    const float* __restrict__ dij,
    const vf4* __restrict__ tbl,
    float* __restrict__ out, int E)
{
    int g    = blockIdx.x * blockDim.x + threadIdx.x;
    int base = g * 4;
    if (base >= E) return;

    float* __restrict__ ec_o = out;
    float* __restrict__ cf_o = out + (size_t)E;
    float* __restrict__ ed_o = out + (size_t)4 * E;
    float* __restrict__ df_o = out + (size_t)5 * E;

    vi4 rr = __builtin_nontemporal_load((const vi4*)(row + base));
    vi4 cc = __builtin_nontemporal_load((const vi4*)(col + base));

    // Issue all 8 gathers up front (clustered, latency overlapped).
    vf4 a0r = tbl[rr.x]; vf4 a0c = tbl[cc.x];
    vf4 a1r = tbl[rr.y]; vf4 a1c = tbl[cc.y];
    vf4 a2r = tbl[rr.z]; vf4 a2c = tbl[cc.z];
    vf4 a3r = tbl[rr.w]; vf4 a3c = tbl[cc.w];

    const float* dp = dij + (size_t)base * 3;
    vf4 d0 = __builtin_nontemporal_load((const vf4*)(dp + 0));
    vf4 d1 = __builtin_nontemporal_load((const vf4*)(dp + 4));
    vf4 d2 = __builtin_nontemporal_load((const vf4*)(dp + 8));

    EdgeOut o0 = edge_compute(a0r, a0c, d0.x, d0.y, d0.z);
    EdgeOut o1 = edge_compute(a1r, a1c, d0.w, d1.x, d1.y);
    EdgeOut o2 = edge_compute(a2r, a2c, d1.z, d1.w, d2.x);
    EdgeOut o3 = edge_compute(a3r, a3c, d2.y, d2.z, d2.w);

    vf4 ec4 = { o0.ec, o1.ec, o2.ec, o3.ec };
    vf4 ed4 = { o0.ed, o1.ed, o2.ed, o3.ed };
    __builtin_nontemporal_store(ec4, (vf4*)(ec_o + base));
    __builtin_nontemporal_store(ed4, (vf4*)(ed_o + base));

    vf4 f0 = { o0.fx, o0.fy, o0.fz, o1.fx };
    vf4 f1 = { o1.fy, o1.fz, o2.fx, o2.fy };
    vf4 f2 = { o2.fz, o3.fx, o3.fy, o3.fz };
    float* cfp = cf_o + (size_t)base * 3;
    __builtin_nontemporal_store(f0, (vf4*)(cfp + 0));
    __builtin_nontemporal_store(f1, (vf4*)(cfp + 4));
    __builtin_nontemporal_store(f2, (vf4*)(cfp + 8));

    vf4 g0 = { o0.gx, o0.gy, o0.gz, o1.gx };
    vf4 g1 = { o1.gy, o1.gz, o2.gx, o2.gy };
    vf4 g2 = { o2.gz, o3.gx, o3.gy, o3.gz };
    float* dfp = df_o + (size_t)base * 3;
    __builtin_nontemporal_store(g0, (vf4*)(dfp + 0));
    __builtin_nontemporal_store(g1, (vf4*)(dfp + 4));
    __builtin_nontemporal_store(g2, (vf4*)(dfp + 8));
}

// Scalar fallback (handles tail / E%4!=0 / tiny workspace).
__global__ __launch_bounds__(256) void bamboo_scalar(
    const int* __restrict__ row, const int* __restrict__ col,
    const float* __restrict__ dij,
    const float* __restrict__ charge, const float* __restrict__ c6a,
    const float* __restrict__ r0a,
    float* __restrict__ out, int E, int start)
{
    int j = start + blockIdx.x * blockDim.x + threadIdx.x;
    if (j >= E) return;
    float* ec_o = out;
    float* cf_o = out + (size_t)E;
    float* ed_o = out + (size_t)4 * E;
    float* df_o = out + (size_t)5 * E;
    int r = row[j], c = col[j];
    vf4 ar = { charge[r], c6a[r], r0a[r], 0.0f };
    vf4 ac = { charge[c], c6a[c], r0a[c], 0.0f };
    EdgeOut o = edge_compute(ar, ac,
                             dij[3 * (size_t)j], dij[3 * (size_t)j + 1], dij[3 * (size_t)j + 2]);
    ec_o[j] = o.ec; ed_o[j] = o.ed;
    cf_o[3 * (size_t)j] = o.fx; cf_o[3 * (size_t)j + 1] = o.fy; cf_o[3 * (size_t)j + 2] = o.fz;
    df_o[3 * (size_t)j] = o.gx; df_o[3 * (size_t)j + 1] = o.gy; df_o[3 * (size_t)j + 2] = o.gz;
}

extern "C" void kernel_launch(void* const* d_in, const int* in_sizes, int n_in,
                              void* d_out, int out_size, void* d_ws, size_t ws_size,
                              hipStream_t stream) {
    const int*   row    = (const int*)d_in[0];
    const int*   col    = (const int*)d_in[1];
    const float* dij    = (const float*)d_in[2];
    const float* charge = (const float*)d_in[3];
    const float* c6a    = (const float*)d_in[4];
    const float* r0a    = (const float*)d_in[5];
    float* out = (float*)d_out;
    int E = in_sizes[0];
    int N = in_sizes[3];

    size_t need = (size_t)N * sizeof(vf4);
    if (ws_size >= need && ((uintptr_t)d_ws % 16) == 0 && (E & 3) == 0) {
        vf4* tbl = (vf4*)d_ws;
        pack_atoms<<<(N + 255) / 256, 256, 0, stream>>>(charge, c6a, r0a, tbl, N);
        int groups = E / 4;
        bamboo_vec4<<<(groups + 255) / 256, 256, 0, stream>>>(row, col, dij, tbl, out, E);
    } else {
        bamboo_scalar<<<(E + 255) / 256, 256, 0, stream>>>(row, col, dij, charge, c6a, r0a, out, E, 0);
    }
}

// Round 4
// 234.929 us; speedup vs baseline: 1.2145x; 1.0247x over previous
//
#include <hip/hip_runtime.h>
#include <math.h>

// -------- physical constants (from reference) --------
#define C_ELE   332.0637f
#define C_EWF   1.12837917f
#define C_EWP   0.3275911f
#define C_A0    0.254829592f
#define C_A1   -0.284496736f
#define C_A2    1.421413741f
#define C_A3   -1.453152027f
#define C_A4    1.061405429f
#define C_BETA  18.7f
#define C_R0    2.2f
#define C_GEW   0.3f
#define C_45P6  8303.765625f   // 4.5^6
#define C_DC6I  1e-6f          // 1 / DISP_CUTOFF^6

typedef float vf4 __attribute__((ext_vector_type(4)));
typedef int   vi4 __attribute__((ext_vector_type(4)));

__device__ __forceinline__ float frcp(float x) { return __builtin_amdgcn_rcpf(x); }

struct EdgeOut { float ec, fx, fy, fz, ed, gx, gy, gz; };

// ar/ac = packed atom records: {charge, c6, r0, pad}
__device__ __forceinline__ EdgeOut edge_compute(
    vf4 ar, vf4 ac, float dx, float dy, float dz)
{
    float r2   = dx * dx + dy * dy + dz * dz;
    float rij  = sqrtf(r2);
    float rinv = frcp(rij);

    // ---- Coulomb ----
    float pref = C_ELE * ar.x * ac.x * rinv;
    float x    = (C_BETA / C_R0) * (rij - C_R0);
    float ax   = fabsf(x);
    float ex   = __expf(-ax);                 // exp(-|x|), stable
    float den  = frcp(1.0f + ex);
    float damp = (x >= 0.0f) ? den : ex * den;          // sigmoid(x)
    float sp   = (fmaxf(x, 0.0f) + __logf(1.0f + ex)) * (1.0f / C_BETA); // softplus(x)/beta
    float s    = rij * (1.0f / C_R0) * frcp(1.0f + sp);

    float grij  = C_GEW * rij;
    float expm2 = __expf(-grij * grij);
    float t     = frcp(1.0f + C_EWP * grij);
    float erfc  = t * (C_A0 + t * (C_A1 + t * (C_A2 + t * (C_A3 + t * C_A4)))) * expm2;

    EdgeOut o;
    o.ec = pref * (s + erfc - 1.0f);
    float fcl = pref * (damp * s * s + erfc + C_EWF * grij * expm2 - 1.0f);
    float fsc = fcl * frcp(r2);
    o.fx = dx * fsc; o.fy = dy * fsc; o.fz = dz * fsc;

    // ---- Dispersion (D3-CSO) ----
    float c6ij  = sqrtf(ar.y * ac.y);
    float r0ij  = 0.5f * (ar.z + ac.z);
    float r6    = r2 * r2 * r2 + C_45P6;
    float r6i   = frcp(r6);
    float e     = __expf(rij - 2.5f * r0ij);
    float onep  = frcp(1.0f + e);
    float cso   = 0.85f + 0.82f * onep;
    o.ed = -c6ij * r6i * cso + c6ij * C_DC6I;
    float r5  = r2 * r2 * rij;
    float fd  = -6.0f * c6ij * r5 * r6i * r6i * cso - c6ij * r6i * (0.82f * e * onep * onep);
    float gsc = fd * rinv;
    o.gx = dx * gsc; o.gy = dy * gsc; o.gz = dz * gsc;
    return o;
}

// Prologue: pack (charge, c6, r0) into one 16B record per atom in d_ws.
__global__ __launch_bounds__(256) void pack_atoms(
    const float* __restrict__ charge, const float* __restrict__ c6a,
    const float* __restrict__ r0a, vf4* __restrict__ tbl, int N)
{
    int i = blockIdx.x * blockDim.x + threadIdx.x;
    if (i < N) {
        vf4 v = { charge[i], c6a[i], r0a[i], 0.0f };
        tbl[i] = v;
    }
}

// 4 edges per thread. All loads are issued as one cluster (pinned with
// sched_barrier) so the wave pays ~2 memory latencies total (idx -> gather),
// then computes entirely out of registers.
__global__ __launch_bounds__(256) void bamboo_vec4(
    const int* __restrict__ row, const int* __restrict__ col,
    const float* __restrict__ dij,
    const vf4* __restrict__ tbl,
    float* __restrict__ out, int E)
{
    int g    = blockIdx.x * blockDim.x + threadIdx.x;
    int base = g * 4;
    if (base >= E) return;

    float* __restrict__ ec_o = out;
    float* __restrict__ cf_o = out + (size_t)E;
    float* __restrict__ ed_o = out + (size_t)4 * E;
    float* __restrict__ df_o = out + (size_t)5 * E;

    // --- load cluster 1: indices + streamed dij ---
    vi4 rr = __builtin_nontemporal_load((const vi4*)(row + base));
    vi4 cc = __builtin_nontemporal_load((const vi4*)(col + base));
    const float* dp = dij + (size_t)base * 3;
    vf4 d0 = __builtin_nontemporal_load((const vf4*)(dp + 0));
    vf4 d1 = __builtin_nontemporal_load((const vf4*)(dp + 4));
    vf4 d2 = __builtin_nontemporal_load((const vf4*)(dp + 8));
    __builtin_amdgcn_sched_barrier(0);   // pin: issue the above before anything below

    // --- load cluster 2: all 8 gathers, back to back ---
    vf4 a0r = tbl[rr.x]; vf4 a0c = tbl[cc.x];
    vf4 a1r = tbl[rr.y]; vf4 a1c = tbl[cc.y];
    vf4 a2r = tbl[rr.z]; vf4 a2c = tbl[cc.z];
    vf4 a3r = tbl[rr.w]; vf4 a3c = tbl[cc.w];
    __builtin_amdgcn_sched_barrier(0);   // pin: all gathers in flight before compute

    EdgeOut o0 = edge_compute(a0r, a0c, d0.x, d0.y, d0.z);
    EdgeOut o1 = edge_compute(a1r, a1c, d0.w, d1.x, d1.y);
    EdgeOut o2 = edge_compute(a2r, a2c, d1.z, d1.w, d2.x);
    EdgeOut o3 = edge_compute(a3r, a3c, d2.y, d2.z, d2.w);

    vf4 ec4 = { o0.ec, o1.ec, o2.ec, o3.ec };
    vf4 ed4 = { o0.ed, o1.ed, o2.ed, o3.ed };
    __builtin_nontemporal_store(ec4, (vf4*)(ec_o + base));
    __builtin_nontemporal_store(ed4, (vf4*)(ed_o + base));

    vf4 f0 = { o0.fx, o0.fy, o0.fz, o1.fx };
    vf4 f1 = { o1.fy, o1.fz, o2.fx, o2.fy };
    vf4 f2 = { o2.fz, o3.fx, o3.fy, o3.fz };
    float* cfp = cf_o + (size_t)base * 3;
    __builtin_nontemporal_store(f0, (vf4*)(cfp + 0));
    __builtin_nontemporal_store(f1, (vf4*)(cfp + 4));
    __builtin_nontemporal_store(f2, (vf4*)(cfp + 8));

    vf4 g0 = { o0.gx, o0.gy, o0.gz, o1.gx };
    vf4 g1 = { o1.gy, o1.gz, o2.gx, o2.gy };
    vf4 g2 = { o2.gz, o3.gx, o3.gy, o3.gz };
    float* dfp = df_o + (size_t)base * 3;
    __builtin_nontemporal_store(g0, (vf4*)(dfp + 0));
    __builtin_nontemporal_store(g1, (vf4*)(dfp + 4));
    __builtin_nontemporal_store(g2, (vf4*)(dfp + 8));
}

// Scalar fallback (handles E%4!=0 / tiny workspace).
__global__ __launch_bounds__(256) void bamboo_scalar(
    const int* __restrict__ row, const int* __restrict__ col,
    const float* __restrict__ dij,
    const float* __restrict__ charge, const float* __restrict__ c6a,
    const float* __restrict__ r0a,
    float* __restrict__ out, int E, int start)
{
    int j = start + blockIdx.x * blockDim.x + threadIdx.x;
    if (j >= E) return;
    float* ec_o = out;
    float* cf_o = out + (size_t)E;
    float* ed_o = out + (size_t)4 * E;
    float* df_o = out + (size_t)5 * E;
    int r = row[j], c = col[j];
    vf4 ar = { charge[r], c6a[r], r0a[r], 0.0f };
    vf4 ac = { charge[c], c6a[c], r0a[c], 0.0f };
    EdgeOut o = edge_compute(ar, ac,
                             dij[3 * (size_t)j], dij[3 * (size_t)j + 1], dij[3 * (size_t)j + 2]);
    ec_o[j] = o.ec; ed_o[j] = o.ed;
    cf_o[3 * (size_t)j] = o.fx; cf_o[3 * (size_t)j + 1] = o.fy; cf_o[3 * (size_t)j + 2] = o.fz;
    df_o[3 * (size_t)j] = o.gx; df_o[3 * (size_t)j + 1] = o.gy; df_o[3 * (size_t)j + 2] = o.gz;
}

extern "C" void kernel_launch(void* const* d_in, const int* in_sizes, int n_in,
                              void* d_out, int out_size, void* d_ws, size_t ws_size,
                              hipStream_t stream) {
    const int*   row    = (const int*)d_in[0];
    const int*   col    = (const int*)d_in[1];
    const float* dij    = (const float*)d_in[2];
    const float* charge = (const float*)d_in[3];
    const float* c6a    = (const float*)d_in[4];
    const float* r0a    = (const float*)d_in[5];
    float* out = (float*)d_out;
    int E = in_sizes[0];
    int N = in_sizes[3];

    size_t need = (size_t)N * sizeof(vf4);
    if (ws_size >= need && ((uintptr_t)d_ws % 16) == 0 && (E & 3) == 0) {
        vf4* tbl = (vf4*)d_ws;
        pack_atoms<<<(N + 255) / 256, 256, 0, stream>>>(charge, c6a, r0a, tbl, N);
        int groups = E / 4;
        bamboo_vec4<<<(groups + 255) / 256, 256, 0, stream>>>(row, col, dij, tbl, out, E);
    } else {
        bamboo_scalar<<<(E + 255) / 256, 256, 0, stream>>>(row, col, dij, charge, c6a, r0a, out, E, 0);
    }
}